// Round 4
// baseline (942.392 us; speedup 1.0000x reference)
//
#include <hip/hip_runtime.h>

// KnowledgeGNN forward, fp32 I/O. Sizes fixed per reference.
#define Dd   64
#define Tt   4096
#define Nn   20000
#define Mm   24096      // T + N
#define Ee   100000
#define Rr   50
#define TOK  768

// K1 block-range layout
#define NB_TOK   256      // Tt/16 rows
#define NB_NODES 1250     // Nn*16/256
#define NB_RELID 4883     // ceil(Ee*Rr/1024)
#define NB_W     800      // Rr*4096/256
#define NB_U     13       // ceil(3200/256)
#define NB_ZERO  95       // ceil((Mm+2)/256)

__device__ __forceinline__ float waveRed(float v){
  #pragma unroll
  for(int o=32;o;o>>=1) v += __shfl_xor(v,o,64);
  return v;
}
__device__ __forceinline__ float4 relu4(float4 v){
  v.x=fmaxf(v.x,0.f); v.y=fmaxf(v.y,0.f); v.z=fmaxf(v.z,0.f); v.w=fmaxf(v.w,0.f);
  return v;
}

// ---------------- K1: fused prep (all sections independent) ----------------
// tok | nodes | relid | W | U | zero(deg,S)
__global__ __launch_bounds__(256) void k_prep(
    const float* __restrict__ A, const float* __restrict__ wl1, const float* __restrict__ bl1,
    const int* __restrict__ ids, const float* __restrict__ kg,
    const float* __restrict__ ea, int* __restrict__ relid,
    const float* __restrict__ rel, const float* __restrict__ w2, const float* __restrict__ b2,
    float* __restrict__ W, const float* __restrict__ a1w, const float* __restrict__ a2w,
    float* __restrict__ U1, float* __restrict__ U2,
    int* __restrict__ deg, float* __restrict__ S,
    float* __restrict__ x){
  int b = blockIdx.x;
  const int t = threadIdx.x, lane = t&63, wave = t>>6;
  if(b < NB_TOK){
    // x[0:T] = A @ wl1 + bl1 ; 4 rows/wave, no LDS (w col reads coalesce, L1-served)
    const int rbase = b*16 + wave*4;
    const float* A0 = A + (size_t)(rbase+0)*TOK;
    const float* A1 = A + (size_t)(rbase+1)*TOK;
    const float* A2 = A + (size_t)(rbase+2)*TOK;
    const float* A3 = A + (size_t)(rbase+3)*TOK;
    float acc0=bl1[lane], acc1=acc0, acc2=acc0, acc3=acc0;
    for(int k=0;k<TOK;k+=4){
      float4 a0 = *(const float4*)&A0[k];
      float4 a1 = *(const float4*)&A1[k];
      float4 a2 = *(const float4*)&A2[k];
      float4 a3 = *(const float4*)&A3[k];
      #pragma unroll
      for(int j=0;j<4;j++){
        float wv = wl1[(size_t)(k+j)*Dd + lane];
        acc0 += ((const float*)&a0)[j]*wv;
        acc1 += ((const float*)&a1)[j]*wv;
        acc2 += ((const float*)&a2)[j]*wv;
        acc3 += ((const float*)&a3)[j]*wv;
      }
    }
    x[(size_t)(rbase+0)*Dd + lane] = acc0;
    x[(size_t)(rbase+1)*Dd + lane] = acc1;
    x[(size_t)(rbase+2)*Dd + lane] = acc2;
    x[(size_t)(rbase+3)*Dd + lane] = acc3;
  } else if(b < NB_TOK+NB_NODES){
    int tt = (b-NB_TOK)*256 + t;             // Nn*16 threads, float4 gather
    int i = tt>>4, c = tt&15;
    ((float4*)x)[(size_t)(Tt+i)*16 + c] = ((const float4*)kg)[(size_t)ids[i]*16 + c];
  } else if(b < NB_TOK+NB_NODES+NB_RELID){
    int tt = (b-NB_TOK-NB_NODES)*256 + t;
    size_t g4 = (size_t)tt*4;
    if(g4 < (size_t)Ee*Rr){
      float4 v = *(const float4*)&ea[g4];
      #pragma unroll
      for(int j=0;j<4;j++){
        if(((const float*)&v)[j] > 0.5f){
          unsigned g = (unsigned)(g4 + j);
          unsigned e = g / 50u;
          relid[e] = (int)(g - e*50u);
        }
      }
    }
  } else if(b < NB_TOK+NB_NODES+NB_RELID+NB_W){
    int tt = (b-NB_TOK-NB_NODES-NB_RELID)*256 + t;   // R*4096
    int r = tt>>12, j = tt&4095;
    float acc = b2[j];
    const float* rp = rel + r*Dd;
    #pragma unroll 8
    for(int d=0;d<Dd;d++) acc += rp[d] * w2[(size_t)d*4096 + j];
    W[tt] = acc > 0.f ? acc : 0.f;
  } else if(b < NB_TOK+NB_NODES+NB_RELID+NB_W+NB_U){
    int tt = (b-NB_TOK-NB_NODES-NB_RELID-NB_W)*256 + t;
    if(tt < Rr*Dd){
      // NOTE: W may be written concurrently by other blocks of this kernel!
      // -> recompute W row here instead of reading the W buffer.
      int r = tt>>6, d = tt&63;
      const float* rp = rel + r*Dd;
      float s1 = 0.f, s2 = 0.f;
      #pragma unroll 4
      for(int o=0;o<Dd;o++){
        float acc = b2[d*Dd+o];
        #pragma unroll 8
        for(int k=0;k<Dd;k++) acc += rp[k] * w2[(size_t)k*4096 + d*Dd + o];
        float w = acc > 0.f ? acc : 0.f;
        s1 += w*a1w[Dd+o]; s2 += w*a2w[Dd+o];
      }
      U1[tt] = s1; U2[tt] = s2;
    }
  } else {
    int tt = (b-NB_TOK-NB_NODES-NB_RELID-NB_W-NB_U)*256 + t;
    if(tt < Mm) deg[tt] = 0;
    else if(tt == Mm)   S[0] = 0.f;
    else if(tt == Mm+1) S[1] = 0.f;
  }
}

// ---------------- CSR build ----------------
__global__ void k_hist(const int* __restrict__ ei, int* __restrict__ deg){
  int e = blockIdx.x*256 + threadIdx.x;
  if(e < Ee) atomicAdd(&deg[ei[Ee+e]], 1);
}

__global__ __launch_bounds__(1024) void k_scan(const int* __restrict__ deg,
    int* __restrict__ rowptr, int* __restrict__ cursor){
  __shared__ int ts[1024];
  int t = threadIdx.x;
  int base = t*24;
  int loc[24];
  int s = 0;
  #pragma unroll
  for(int j=0;j<24;j++){
    int idx = base+j;
    int d = (idx < Mm) ? deg[idx] : 0;
    loc[j] = s; s += d;
  }
  ts[t] = s;
  __syncthreads();
  for(int off=1; off<1024; off<<=1){
    int add = (t>=off) ? ts[t-off] : 0;
    __syncthreads();
    ts[t] += add;
    __syncthreads();
  }
  int excl = ts[t] - s;
  #pragma unroll
  for(int j=0;j<24;j++){
    int idx = base+j;
    if(idx < Mm){ int v = excl + loc[j]; rowptr[idx] = v; cursor[idx] = v; }
  }
  if(t==1023) rowptr[Mm] = ts[1023];
}

__global__ void k_fill(const int* __restrict__ ei, int* __restrict__ cursor,
                       int* __restrict__ eidx){
  int e = blockIdx.x*256 + threadIdx.x;
  if(e < Ee){
    int d = ei[Ee+e];
    int pos = atomicAdd(&cursor[d], 1);
    eidx[pos] = e;
  }
}

// ---------------- per-layer kernels ----------------
// Fused: y = relu?(x) @ root + bias   AND   p[i] = relu?(x[i]) . aw[0:64]
__global__ __launch_bounds__(256) void k_rootp(const float* __restrict__ x,
    const float* __restrict__ root, const float* __restrict__ bias,
    const float* __restrict__ aw, float* __restrict__ y, float* __restrict__ p,
    int dorelu){
  __shared__ float rs[Dd][Dd];
  const int t = threadIdx.x, lane = t&63, wave = t>>6;
  const int rbase = blockIdx.x*16 + wave*4;
  #pragma unroll
  for(int i=0;i<4;i++){
    int f = t + 256*i;
    int kk = f>>4, c4 = (f&15)*4;
    *(float4*)&rs[kk][c4] = *(const float4*)&root[(size_t)kk*Dd + c4];
  }
  __syncthreads();
  float acc0=bias[lane], acc1=acc0, acc2=acc0, acc3=acc0;
  #pragma unroll 4
  for(int k=0;k<64;k+=4){
    float4 x0 = *(const float4*)&x[(size_t)(rbase+0)*Dd + k];
    float4 x1 = *(const float4*)&x[(size_t)(rbase+1)*Dd + k];
    float4 x2 = *(const float4*)&x[(size_t)(rbase+2)*Dd + k];
    float4 x3 = *(const float4*)&x[(size_t)(rbase+3)*Dd + k];
    if(dorelu){ x0=relu4(x0); x1=relu4(x1); x2=relu4(x2); x3=relu4(x3); }
    #pragma unroll
    for(int j=0;j<4;j++){
      float wv = rs[k+j][lane];
      acc0 += ((const float*)&x0)[j]*wv;
      acc1 += ((const float*)&x1)[j]*wv;
      acc2 += ((const float*)&x2)[j]*wv;
      acc3 += ((const float*)&x3)[j]*wv;
    }
  }
  y[(size_t)(rbase+0)*Dd + lane] = acc0;
  y[(size_t)(rbase+1)*Dd + lane] = acc1;
  y[(size_t)(rbase+2)*Dd + lane] = acc2;
  y[(size_t)(rbase+3)*Dd + lane] = acc3;
  float av = aw[lane];
  #pragma unroll
  for(int i=0;i<4;i++){
    float xl = x[(size_t)(rbase+i)*Dd + lane];
    if(dorelu) xl = fmaxf(xl, 0.f);
    float pv = waveRed(xl*av);
    if(lane==0) p[rbase+i] = pv;
  }
}

// expa[e] = exp(relu?(x[src]).u_rel + p[dst] + ab); S += sum(expa)
__global__ __launch_bounds__(256) void k_att(const float* __restrict__ x,
    const int* __restrict__ ei, const int* __restrict__ relid,
    const float* __restrict__ U, const float* __restrict__ p,
    const float* __restrict__ ab, float* __restrict__ expa, float* __restrict__ S,
    int dorelu){
  __shared__ float sw[4];
  int lane = threadIdx.x&63, wid = threadIdx.x>>6;
  int gw = blockIdx.x*4 + wid;            // 4096 waves, grid-stride
  float ab0 = ab[0];
  float acc = 0.f;
  for(int e = gw; e < Ee; e += 4096){
    int src = ei[e], dst = ei[Ee+e], r = relid[e];
    float xv = x[(size_t)src*Dd + lane];
    if(dorelu) xv = fmaxf(xv, 0.f);
    float v = waveRed(xv * U[r*Dd + lane]);
    float ex = expf(v + p[dst] + ab0);    // same on all lanes
    if(lane==0) expa[e] = ex;
    acc += ex;
  }
  if(lane==0) sw[wid] = acc;
  __syncthreads();
  if(threadIdx.x==0) atomicAdd(S, sw[0]+sw[1]+sw[2]+sw[3]);
}

// y[dst] += (1/S) * sum_{e in bucket(dst)} expa[e]*relu?(x[src_e])  (no atomics)
__global__ __launch_bounds__(256) void k_aggr(const float* __restrict__ x,
    const int* __restrict__ ei, const int* __restrict__ rowptr,
    const int* __restrict__ eidx, const float* __restrict__ expa,
    const float* __restrict__ S, float* __restrict__ y, int dorelu){
  int lane = threadIdx.x&63, wid = threadIdx.x>>6;
  int dst = blockIdx.x*4 + wid;           // grid covers exactly Mm
  float invS = 1.f / S[0];
  int j0 = rowptr[dst], j1 = rowptr[dst+1];
  float acc = 0.f;
  for(int j=j0; j<j1; j++){
    int e = eidx[j];
    float a = expa[e];
    int src = ei[e];
    float xv = x[(size_t)src*Dd + lane];
    if(dorelu) xv = fmaxf(xv, 0.f);
    acc += a*xv;
  }
  y[(size_t)dst*Dd + lane] += acc * invS;
}

// ---------------- outputs ----------------
__global__ __launch_bounds__(256) void k_out(const float* __restrict__ fx,
    const float* __restrict__ w, const float* __restrict__ b, float* __restrict__ out){
  __shared__ float aT[Dd][36];
  __shared__ float ws[Dd][128];
  const int t = threadIdx.x;
  const int r0 = blockIdx.x*32, co = blockIdx.y*128;
  #pragma unroll
  for(int i=0;i<2;i++){
    int f = t + 256*i;
    int r = f>>4, k4 = (f&15)*4;
    float4 v = *(const float4*)&fx[(size_t)(r0+r)*Dd + k4];
    aT[k4+0][r]=v.x; aT[k4+1][r]=v.y; aT[k4+2][r]=v.z; aT[k4+3][r]=v.w;
  }
  #pragma unroll
  for(int i=0;i<8;i++){
    int f = t + 256*i;
    int kk = f>>5, c4 = (f&31)*4;
    *(float4*)&ws[kk][c4] = *(const float4*)&w[(size_t)kk*TOK + co + c4];
  }
  __syncthreads();
  const int tr = t>>5, tc = t&31;
  const int rb = tr*4, cb = tc*4;
  float4 bv = *(const float4*)&b[co+cb];
  float acc[4][4];
  #pragma unroll
  for(int i=0;i<4;i++){ acc[i][0]=bv.x; acc[i][1]=bv.y; acc[i][2]=bv.z; acc[i][3]=bv.w; }
  #pragma unroll 8
  for(int k=0;k<Dd;k++){
    float4 a  = *(const float4*)&aT[k][rb];
    float4 wv = *(const float4*)&ws[k][cb];
    #pragma unroll
    for(int i=0;i<4;i++){
      float av = ((const float*)&a)[i];
      acc[i][0] += av*wv.x; acc[i][1] += av*wv.y;
      acc[i][2] += av*wv.z; acc[i][3] += av*wv.w;
    }
  }
  #pragma unroll
  for(int i=0;i<4;i++){
    float4 o; o.x=acc[i][0]; o.y=acc[i][1]; o.z=acc[i][2]; o.w=acc[i][3];
    *(float4*)&out[(size_t)(r0+rb+i)*TOK + co + cb] = o;
  }
}

// fused kge (blocks 0..511) + nt (blocks 512..606)
__global__ void k_loss(const float* __restrict__ fx, const int* __restrict__ ei,
    const int* __restrict__ relid, const float* __restrict__ rel,
    const int* __restrict__ lab, const float* __restrict__ wnt,
    const float* __restrict__ bnt, float* __restrict__ kgep, float* __restrict__ ntp){
  __shared__ float sr[4];
  if(blockIdx.x < 512){
    int wid = threadIdx.x>>6, lane = threadIdx.x&63;
    int gw = blockIdx.x*4 + wid;
    float acc = 0.f;
    for(int e=gw; e<Ee; e+=2048){
      int r = relid[e];
      if(r < 47){
        int src = ei[e], dst = ei[Ee+e];
        float d = fx[(size_t)src*Dd + lane] + rel[r*Dd + lane] - fx[(size_t)dst*Dd + lane];
        acc += d*d;
      }
    }
    acc = waveRed(acc);
    if(lane==0) sr[wid] = acc;
    __syncthreads();
    if(threadIdx.x==0) kgep[blockIdx.x] = sr[0]+sr[1]+sr[2]+sr[3];
  } else {
    int nb = blockIdx.x - 512;
    int i = nb*256 + threadIdx.x;
    float contrib = 0.f;
    if(i < Mm){
      const float* r = fx + (size_t)i*Dd;
      float l0 = bnt[0], l1 = bnt[1], l2 = bnt[2];
      #pragma unroll 8
      for(int k=0;k<Dd;k++){
        float f = r[k];
        l0 += f*wnt[k*3+0]; l1 += f*wnt[k*3+1]; l2 += f*wnt[k*3+2];
      }
      float mx = fmaxf(l0, fmaxf(l1,l2));
      float lse = logf(expf(l0-mx)+expf(l1-mx)+expf(l2-mx)) + mx;
      int lb = lab[i];
      float lp = (lb==0 ? l0 : (lb==1 ? l1 : l2)) - lse;
      contrib = -lp;
    }
    float s = waveRed(contrib);
    if((threadIdx.x&63)==0) sr[threadIdx.x>>6] = s;
    __syncthreads();
    if(threadIdx.x==0) ntp[nb] = sr[0]+sr[1]+sr[2]+sr[3];
  }
}

__global__ void k_final(const float* __restrict__ kgep, const float* __restrict__ ntp,
                        float* __restrict__ out){
  __shared__ float sa[4], sb[4];
  float s = 0.f, t = 0.f;
  for(int i=threadIdx.x;i<512;i+=256) s += kgep[i];
  for(int i=threadIdx.x;i<95;i+=256)  t += ntp[i];
  s = waveRed(s); t = waveRed(t);
  if((threadIdx.x&63)==0){ sa[threadIdx.x>>6] = s; sb[threadIdx.x>>6] = t; }
  __syncthreads();
  if(threadIdx.x==0){
    size_t base = (size_t)Mm*TOK;
    out[base+0] = (sa[0]+sa[1]+sa[2]+sa[3]) / (float)(Ee*Dd);
    out[base+1] = (sb[0]+sb[1]+sb[2]+sb[3]) / (float)Mm;
  }
}

extern "C" void kernel_launch(void* const* d_in, const int* in_sizes, int n_in,
                              void* d_out, int out_size, void* d_ws, size_t ws_size,
                              hipStream_t stream) {
  const int*   node_ids = (const int*)d_in[0];
  const int*   ei       = (const int*)d_in[1];
  const float* eattr    = (const float*)d_in[2];
  const float* tokemb   = (const float*)d_in[3];
  const int*   labels   = (const int*)d_in[4];
  const float* kg       = (const float*)d_in[5];
  const float* rel      = (const float*)d_in[6];
  const float* w_e2     = (const float*)d_in[7];
  const float* b_e2     = (const float*)d_in[8];
  const float* a1w      = (const float*)d_in[9];
  const float* a1b      = (const float*)d_in[10];
  const float* root1    = (const float*)d_in[11];
  const float* bias1    = (const float*)d_in[12];
  const float* a2w      = (const float*)d_in[13];
  const float* a2b      = (const float*)d_in[14];
  const float* root2    = (const float*)d_in[15];
  const float* bias2    = (const float*)d_in[16];
  const float* wlin1    = (const float*)d_in[17];
  const float* blin1    = (const float*)d_in[18];
  const float* wlin2    = (const float*)d_in[19];
  const float* blin2    = (const float*)d_in[20];
  const float* wnt      = (const float*)d_in[21];
  const float* bnt      = (const float*)d_in[22];

  float* wsb = (float*)d_ws;
  float* x    = wsb;                      // M*64
  float* h    = x  + (size_t)Mm*Dd;
  float* fx   = h  + (size_t)Mm*Dd;
  float* W    = fx + (size_t)Mm*Dd;       // 50*4096
  float* U1   = W  + Rr*4096;             // 3200
  float* U2   = U1 + Rr*Dd;
  float* expa = U2 + Rr*Dd;               // E
  float* p    = expa + Ee;                // M
  float* S    = p + Mm;                   // 2
  float* kgep = S + 2;                    // 512
  float* ntp  = kgep + 512;               // 128
  int* relid  = (int*)(ntp + 128);        // E
  int* deg    = relid + Ee;               // M
  int* rowptr = deg + Mm;                 // M+1
  int* cursor = rowptr + Mm + 1;          // M
  int* eidx   = cursor + Mm;              // E
  float* out  = (float*)d_out;

  // ---- prep (fused) + CSR build ----
  int nb1 = NB_TOK+NB_NODES+NB_RELID+NB_W+NB_U+NB_ZERO;
  k_prep<<<nb1, 256, 0, stream>>>(tokemb, wlin1, blin1, node_ids, kg, eattr, relid,
                                  rel, w_e2, b_e2, W, a1w, a2w, U1, U2, deg, S, x);
  k_hist<<<(Ee+255)/256, 256, 0, stream>>>(ei, deg);
  k_scan<<<1, 1024, 0, stream>>>(deg, rowptr, cursor);
  k_fill<<<(Ee+255)/256, 256, 0, stream>>>(ei, cursor, eidx);

  // ---- layer 1: x -> h ----
  k_rootp<<<Mm/16, 256, 0, stream>>>(x, root1, bias1, a1w, h, p, 0);
  k_att  <<<1024, 256, 0, stream>>>(x, ei, relid, U1, p, a1b, expa, S, 0);
  k_aggr <<<Mm/4, 256, 0, stream>>>(x, ei, rowptr, eidx, expa, S, h, 0);

  // ---- layer 2: relu(h) -> fx ----
  k_rootp<<<Mm/16, 256, 0, stream>>>(h, root2, bias2, a2w, fx, p, 1);
  k_att  <<<1024, 256, 0, stream>>>(h, ei, relid, U2, p, a2b, expa, S+1, 1);
  k_aggr <<<Mm/4, 256, 0, stream>>>(h, ei, rowptr, eidx, expa, S+1, fx, 1);

  // ---- outputs ----
  dim3 og(Mm/32, TOK/128);
  k_out  <<<og, 256, 0, stream>>>(fx, wlin2, blin2, out);
  k_loss <<<607, 256, 0, stream>>>(fx, ei, relid, rel, labels, wnt, bnt, kgep, ntp);
  k_final<<<1, 256, 0, stream>>>(kgep, ntp, out);
}

// Round 5
// 448.735 us; speedup vs baseline: 2.1001x; 2.1001x over previous
//
#include <hip/hip_runtime.h>

// KnowledgeGNN forward, fp32 I/O. Sizes fixed per reference.
#define Dd   64
#define Tt   4096
#define Nn   20000
#define Mm   24096      // T + N
#define Ee   100000
#define Rr   50
#define TOK  768

// k_prep block-range layout: tok | nodes | relid | W | zero
#define NB_TOK   256      // Tt/16 rows
#define NB_NODES 1250     // Nn*16/256
#define NB_RELID 4883     // ceil(Ee*Rr/1024)
#define NB_W     800      // Rr*4096/256
#define NB_ZERO  95       // ceil((Mm+4)/256)
// k_mid block-range layout: hist | U | p1
#define NBM_HIST 391
#define NBM_U    13
#define NBM_P    6024     // Mm/4 rows, 1 row per wave

__device__ __forceinline__ float waveRed(float v){
  #pragma unroll
  for(int o=32;o;o>>=1) v += __shfl_xor(v,o,64);
  return v;
}

// ---------------- K1: fused prep ----------------
__global__ __launch_bounds__(256) void k_prep(
    const float* __restrict__ A, const float* __restrict__ wl1, const float* __restrict__ bl1,
    const int* __restrict__ ids, const float* __restrict__ kg,
    const float* __restrict__ ea, int* __restrict__ relid,
    const float* __restrict__ rel, const float* __restrict__ w2, const float* __restrict__ b2,
    float* __restrict__ W, int* __restrict__ deg, float* __restrict__ S,
    float* __restrict__ x){
  int b = blockIdx.x;
  const int t = threadIdx.x, lane = t&63, wave = t>>6;
  if(b < NB_TOK){
    // x[0:T] = A @ wl1 + bl1 ; 4 rows/wave; wl1 col reads are wave-coalesced, L1/L2-served
    const int rbase = b*16 + wave*4;
    const float* A0 = A + (size_t)(rbase+0)*TOK;
    const float* A1 = A + (size_t)(rbase+1)*TOK;
    const float* A2 = A + (size_t)(rbase+2)*TOK;
    const float* A3 = A + (size_t)(rbase+3)*TOK;
    float acc0=bl1[lane], acc1=acc0, acc2=acc0, acc3=acc0;
    for(int k=0;k<TOK;k+=4){
      float4 a0 = *(const float4*)&A0[k];
      float4 a1 = *(const float4*)&A1[k];
      float4 a2 = *(const float4*)&A2[k];
      float4 a3 = *(const float4*)&A3[k];
      #pragma unroll
      for(int j=0;j<4;j++){
        float wv = wl1[(size_t)(k+j)*Dd + lane];
        acc0 += ((const float*)&a0)[j]*wv;
        acc1 += ((const float*)&a1)[j]*wv;
        acc2 += ((const float*)&a2)[j]*wv;
        acc3 += ((const float*)&a3)[j]*wv;
      }
    }
    x[(size_t)(rbase+0)*Dd + lane] = acc0;
    x[(size_t)(rbase+1)*Dd + lane] = acc1;
    x[(size_t)(rbase+2)*Dd + lane] = acc2;
    x[(size_t)(rbase+3)*Dd + lane] = acc3;
  } else if(b < NB_TOK+NB_NODES){
    int tt = (b-NB_TOK)*256 + t;             // Nn*16 threads, float4 gather
    int i = tt>>4, c = tt&15;
    ((float4*)x)[(size_t)(Tt+i)*16 + c] = ((const float4*)kg)[(size_t)ids[i]*16 + c];
  } else if(b < NB_TOK+NB_NODES+NB_RELID){
    int tt = (b-NB_TOK-NB_NODES)*256 + t;
    size_t g4 = (size_t)tt*4;
    if(g4 < (size_t)Ee*Rr){
      float4 v = *(const float4*)&ea[g4];
      #pragma unroll
      for(int j=0;j<4;j++){
        if(((const float*)&v)[j] > 0.5f){
          unsigned g = (unsigned)(g4 + j);
          unsigned e = g / 50u;
          relid[e] = (int)(g - e*50u);
        }
      }
    }
  } else if(b < NB_TOK+NB_NODES+NB_RELID+NB_W){
    int tt = (b-NB_TOK-NB_NODES-NB_RELID)*256 + t;   // R*4096
    int r = tt>>12, j = tt&4095;
    float acc = b2[j];
    const float* rp = rel + r*Dd;
    #pragma unroll 8
    for(int d=0;d<Dd;d++) acc += rp[d] * w2[(size_t)d*4096 + j];
    W[tt] = acc > 0.f ? acc : 0.f;
  } else {
    int tt = (b-NB_TOK-NB_NODES-NB_RELID-NB_W)*256 + t;
    if(tt < Mm) deg[tt] = 0;
    else if(tt < Mm+4) S[tt-Mm] = 0.f;
  }
}

// ---------------- K2: fused hist | U | p1 (all depend only on k_prep) ----------------
__global__ __launch_bounds__(256) void k_mid(const int* __restrict__ ei,
    int* __restrict__ deg, const float* __restrict__ W,
    const float* __restrict__ a1w, const float* __restrict__ a2w,
    float* __restrict__ U1, float* __restrict__ U2,
    const float* __restrict__ x, float* __restrict__ p){
  int b = blockIdx.x;
  const int t = threadIdx.x, lane = t&63, wave = t>>6;
  if(b < NBM_HIST){
    int e = b*256 + t;
    if(e < Ee) atomicAdd(&deg[ei[Ee+e]], 1);
  } else if(b < NBM_HIST+NBM_U){
    int tt = (b-NBM_HIST)*256 + t;           // R*64 = 3200
    if(tt < Rr*Dd){
      const float* wp = W + (size_t)(tt>>6)*4096 + (size_t)(tt&63)*Dd;
      float s1 = 0.f, s2 = 0.f;
      #pragma unroll 8
      for(int o=0;o<Dd;o++){ float w = wp[o]; s1 += w*a1w[Dd+o]; s2 += w*a2w[Dd+o]; }
      U1[tt] = s1; U2[tt] = s2;
    }
  } else {
    int i = (b-NBM_HIST-NBM_U)*4 + wave;     // one row per wave, layer-1 p (no relu)
    float pv = waveRed(x[(size_t)i*Dd + lane] * a1w[lane]);
    if(lane==0) p[i] = pv;
  }
}

// ---------------- CSR build ----------------
__global__ __launch_bounds__(1024) void k_scan(const int* __restrict__ deg,
    int* __restrict__ rowptr, int* __restrict__ cursor){
  __shared__ int ts[1024];
  int t = threadIdx.x;
  int base = t*24;
  int loc[24];
  int s = 0;
  #pragma unroll
  for(int j=0;j<24;j++){
    int idx = base+j;
    int d = (idx < Mm) ? deg[idx] : 0;
    loc[j] = s; s += d;
  }
  ts[t] = s;
  __syncthreads();
  for(int off=1; off<1024; off<<=1){
    int add = (t>=off) ? ts[t-off] : 0;
    __syncthreads();
    ts[t] += add;
    __syncthreads();
  }
  int excl = ts[t] - s;
  #pragma unroll
  for(int j=0;j<24;j++){
    int idx = base+j;
    if(idx < Mm){ int v = excl + loc[j]; rowptr[idx] = v; cursor[idx] = v; }
  }
  if(t==1023) rowptr[Mm] = ts[1023];
}

__global__ void k_fill(const int* __restrict__ ei, int* __restrict__ cursor,
                       int* __restrict__ eidx){
  int e = blockIdx.x*256 + threadIdx.x;
  if(e < Ee){
    int d = ei[Ee+e];
    int pos = atomicAdd(&cursor[d], 1);
    eidx[pos] = e;
  }
}

// ---------------- attention: expa[e] = exp(relu?(x[src]).u_r + p[dst] + ab); S += sum ----------------
__global__ __launch_bounds__(256) void k_att(const float* __restrict__ x,
    const int* __restrict__ ei, const int* __restrict__ relid,
    const float* __restrict__ U, const float* __restrict__ p,
    const float* __restrict__ ab, float* __restrict__ expa, float* __restrict__ S,
    int dorelu){
  __shared__ float sw[4];
  int lane = threadIdx.x&63, wid = threadIdx.x>>6;
  int gw = blockIdx.x*4 + wid;            // 8192 waves, grid-stride
  float ab0 = ab[0];
  float acc = 0.f;
  for(int e = gw; e < Ee; e += 8192){
    int src = ei[e], dst = ei[Ee+e], r = relid[e];
    float xv = x[(size_t)src*Dd + lane];
    if(dorelu) xv = fmaxf(xv, 0.f);
    float v = waveRed(xv * U[r*Dd + lane]);
    float ex = expf(v + p[dst] + ab0);    // lane-uniform
    if(lane==0) expa[e] = ex;
    acc += ex;
  }
  if(lane==0) sw[wid] = acc;
  __syncthreads();
  if(threadIdx.x==0) atomicAdd(S, sw[0]+sw[1]+sw[2]+sw[3]);
}

// ---------------- aggregate + fused root matmul (+ next-layer p) ----------------
// y[dst] = (1/S)*sum_{e in bucket(dst)} expa[e]*relu?(x[src_e]) + relu?(x[dst])@root + bias
__global__ __launch_bounds__(256) void k_aggr(const float* __restrict__ x,
    const int* __restrict__ ei, const int* __restrict__ rowptr,
    const int* __restrict__ eidx, const float* __restrict__ expa,
    const float* __restrict__ S, const float* __restrict__ root,
    const float* __restrict__ bias, const float* __restrict__ awn,
    float* __restrict__ y, float* __restrict__ pnext, int dorelu){
  int lane = threadIdx.x&63, wid = threadIdx.x>>6;
  int dst = blockIdx.x*4 + wid;           // grid covers exactly Mm
  float invS = 1.f / S[0];
  int j0 = rowptr[dst], j1 = rowptr[dst+1];
  float acc = 0.f;
  for(int j=j0; j<j1; j++){
    int e = eidx[j];
    float a = expa[e];
    int src = ei[e];
    float xv = x[(size_t)src*Dd + lane];
    if(dorelu) xv = fmaxf(xv, 0.f);
    acc += a*xv;
  }
  acc *= invS;
  // root term via lane-broadcast of this row
  float xd = x[(size_t)dst*Dd + lane];
  if(dorelu) xd = fmaxf(xd, 0.f);
  float rsum = bias[lane];
  #pragma unroll 16
  for(int k=0;k<Dd;k++){
    float xk = __shfl(xd, k, 64);
    rsum += xk * root[k*Dd + lane];
  }
  float o = acc + rsum;
  y[(size_t)dst*Dd + lane] = o;
  if(pnext){
    float orl = fmaxf(o, 0.f);            // next layer reads relu(h)
    float pv = waveRed(orl * awn[lane]);
    if(lane==0) pnext[dst] = pv;
  }
}

// ---------------- losses: atomic accumulate into S[2] (kge), S[3] (nt) ----------------
__global__ void k_loss(const float* __restrict__ fx, const int* __restrict__ ei,
    const int* __restrict__ relid, const float* __restrict__ rel,
    const int* __restrict__ lab, const float* __restrict__ wnt,
    const float* __restrict__ bnt, float* __restrict__ S){
  __shared__ float sr[4];
  if(blockIdx.x < 512){
    int wid = threadIdx.x>>6, lane = threadIdx.x&63;
    int gw = blockIdx.x*4 + wid;
    float acc = 0.f;
    for(int e=gw; e<Ee; e+=2048){
      int r = relid[e];
      if(r < 47){
        int src = ei[e], dst = ei[Ee+e];
        float d = fx[(size_t)src*Dd + lane] + rel[r*Dd + lane] - fx[(size_t)dst*Dd + lane];
        acc += d*d;
      }
    }
    acc = waveRed(acc);
    if(lane==0) sr[wid] = acc;
    __syncthreads();
    if(threadIdx.x==0) atomicAdd(&S[2], sr[0]+sr[1]+sr[2]+sr[3]);
  } else {
    int nb = blockIdx.x - 512;
    int i = nb*256 + threadIdx.x;
    float contrib = 0.f;
    if(i < Mm){
      const float* r = fx + (size_t)i*Dd;
      float l0 = bnt[0], l1 = bnt[1], l2 = bnt[2];
      #pragma unroll 8
      for(int k=0;k<Dd;k++){
        float f = r[k];
        l0 += f*wnt[k*3+0]; l1 += f*wnt[k*3+1]; l2 += f*wnt[k*3+2];
      }
      float mx = fmaxf(l0, fmaxf(l1,l2));
      float lse = logf(expf(l0-mx)+expf(l1-mx)+expf(l2-mx)) + mx;
      int lb = lab[i];
      float lp = (lb==0 ? l0 : (lb==1 ? l1 : l2)) - lse;
      contrib = -lp;
    }
    float s = waveRed(contrib);
    if((threadIdx.x&63)==0) sr[threadIdx.x>>6] = s;
    __syncthreads();
    if(threadIdx.x==0) atomicAdd(&S[3], sr[0]+sr[1]+sr[2]+sr[3]);
  }
}

// ---------------- out = fx @ w_lin2 + b_lin2 (+ scalar outputs; k_loss done) ----------------
__global__ __launch_bounds__(256) void k_out(const float* __restrict__ fx,
    const float* __restrict__ w, const float* __restrict__ b,
    const float* __restrict__ S, float* __restrict__ out){
  if(blockIdx.x==0 && blockIdx.y==0 && threadIdx.x==0){
    size_t base = (size_t)Mm*TOK;
    out[base+0] = S[2] / (float)(Ee*Dd);
    out[base+1] = S[3] / (float)Mm;
  }
  __shared__ float aT[Dd][36];
  __shared__ float ws[Dd][128];
  const int t = threadIdx.x;
  const int r0 = blockIdx.x*32, co = blockIdx.y*128;
  #pragma unroll
  for(int i=0;i<2;i++){
    int f = t + 256*i;
    int r = f>>4, k4 = (f&15)*4;
    float4 v = *(const float4*)&fx[(size_t)(r0+r)*Dd + k4];
    aT[k4+0][r]=v.x; aT[k4+1][r]=v.y; aT[k4+2][r]=v.z; aT[k4+3][r]=v.w;
  }
  #pragma unroll
  for(int i=0;i<8;i++){
    int f = t + 256*i;
    int kk = f>>5, c4 = (f&31)*4;
    *(float4*)&ws[kk][c4] = *(const float4*)&w[(size_t)kk*TOK + co + c4];
  }
  __syncthreads();
  const int tr = t>>5, tc = t&31;
  const int rb = tr*4, cb = tc*4;
  float4 bv = *(const float4*)&b[co+cb];
  float acc[4][4];
  #pragma unroll
  for(int i=0;i<4;i++){ acc[i][0]=bv.x; acc[i][1]=bv.y; acc[i][2]=bv.z; acc[i][3]=bv.w; }
  #pragma unroll 8
  for(int k=0;k<Dd;k++){
    float4 a  = *(const float4*)&aT[k][rb];
    float4 wv = *(const float4*)&ws[k][cb];
    #pragma unroll
    for(int i=0;i<4;i++){
      float av = ((const float*)&a)[i];
      acc[i][0] += av*wv.x; acc[i][1] += av*wv.y;
      acc[i][2] += av*wv.z; acc[i][3] += av*wv.w;
    }
  }
  #pragma unroll
  for(int i=0;i<4;i++){
    float4 o; o.x=acc[i][0]; o.y=acc[i][1]; o.z=acc[i][2]; o.w=acc[i][3];
    *(float4*)&out[(size_t)(r0+rb+i)*TOK + co + cb] = o;
  }
}

extern "C" void kernel_launch(void* const* d_in, const int* in_sizes, int n_in,
                              void* d_out, int out_size, void* d_ws, size_t ws_size,
                              hipStream_t stream) {
  const int*   node_ids = (const int*)d_in[0];
  const int*   ei       = (const int*)d_in[1];
  const float* eattr    = (const float*)d_in[2];
  const float* tokemb   = (const float*)d_in[3];
  const int*   labels   = (const int*)d_in[4];
  const float* kg       = (const float*)d_in[5];
  const float* rel      = (const float*)d_in[6];
  const float* w_e2     = (const float*)d_in[7];
  const float* b_e2     = (const float*)d_in[8];
  const float* a1w      = (const float*)d_in[9];
  const float* a1b      = (const float*)d_in[10];
  const float* root1    = (const float*)d_in[11];
  const float* bias1    = (const float*)d_in[12];
  const float* a2w      = (const float*)d_in[13];
  const float* a2b      = (const float*)d_in[14];
  const float* root2    = (const float*)d_in[15];
  const float* bias2    = (const float*)d_in[16];
  const float* wlin1    = (const float*)d_in[17];
  const float* blin1    = (const float*)d_in[18];
  const float* wlin2    = (const float*)d_in[19];
  const float* blin2    = (const float*)d_in[20];
  const float* wnt      = (const float*)d_in[21];
  const float* bnt      = (const float*)d_in[22];

  float* wsb = (float*)d_ws;
  float* x    = wsb;                      // M*64
  float* h    = x  + (size_t)Mm*Dd;
  float* fx   = h  + (size_t)Mm*Dd;
  float* W    = fx + (size_t)Mm*Dd;       // 50*4096
  float* U1   = W  + Rr*4096;             // 3200
  float* U2   = U1 + Rr*Dd;
  float* expa = U2 + Rr*Dd;               // E
  float* p    = expa + Ee;                // M
  float* S    = p + Mm;                   // 4: den1, den2, kge, nt
  int* relid  = (int*)(S + 4);            // E
  int* deg    = relid + Ee;               // M
  int* rowptr = deg + Mm;                 // M+1
  int* cursor = rowptr + Mm + 1;          // M
  int* eidx   = cursor + Mm;              // E
  float* out  = (float*)d_out;

  // ---- prep + CSR ----
  k_prep<<<NB_TOK+NB_NODES+NB_RELID+NB_W+NB_ZERO, 256, 0, stream>>>(
      tokemb, wlin1, blin1, node_ids, kg, eattr, relid, rel, w_e2, b_e2, W, deg, S, x);
  k_mid <<<NBM_HIST+NBM_U+NBM_P, 256, 0, stream>>>(ei, deg, W, a1w, a2w, U1, U2, x, p);
  k_scan<<<1, 1024, 0, stream>>>(deg, rowptr, cursor);
  k_fill<<<(Ee+255)/256, 256, 0, stream>>>(ei, cursor, eidx);

  // ---- layer 1: x -> h (writes p2 into p) ----
  k_att <<<2048, 256, 0, stream>>>(x, ei, relid, U1, p, a1b, expa, S, 0);
  k_aggr<<<Mm/4, 256, 0, stream>>>(x, ei, rowptr, eidx, expa, S, root1, bias1, a2w, h, p, 0);

  // ---- layer 2: relu(h) -> fx ----
  k_att <<<2048, 256, 0, stream>>>(h, ei, relid, U2, p, a2b, expa, S+1, 1);
  k_aggr<<<Mm/4, 256, 0, stream>>>(h, ei, rowptr, eidx, expa, S+1, root2, bias2, (const float*)0, fx, (float*)0, 1);

  // ---- losses then output GEMM (+ scalars) ----
  k_loss<<<607, 256, 0, stream>>>(fx, ei, relid, rel, labels, wnt, bnt, S);
  dim3 og(Mm/32, TOK/128);
  k_out <<<og, 256, 0, stream>>>(fx, wlin2, blin2, S, out);
}

// Round 6
// 420.490 us; speedup vs baseline: 2.2412x; 1.0672x over previous
//
#include <hip/hip_runtime.h>

// KnowledgeGNN forward, fp32 I/O. Sizes fixed per reference.
#define Dd   64
#define Tt   4096
#define Nn   20000
#define Mm   24096      // T + N
#define Ee   100000
#define Rr   50
#define TOK  768

// k_prep block-range layout: tok | nodes | relid | W | zero
#define NB_TOK   512      // Tt/8 rows per block
#define NB_NODES 1250     // Nn*16/256
#define NB_RELID 4883     // ceil(Ee*Rr/1024)
#define NB_W     800      // Rr*4096/256
#define NB_ZERO  95       // ceil((Mm+4)/256)
// k_mid block-range layout: hist | U | p1
#define NBM_HIST 391
#define NBM_U    13
#define NBM_P    6024     // Mm/4 rows, 1 row per wave
// k_attf: fill | att
#define NBA_FILL 391
#define NBA_ATT  2048

__device__ __forceinline__ float waveRed(float v){
  #pragma unroll
  for(int o=32;o;o>>=1) v += __shfl_xor(v,o,64);
  return v;
}

// ---------------- K1: fused prep ----------------
__global__ __launch_bounds__(256) void k_prep(
    const float* __restrict__ A, const float* __restrict__ wl1, const float* __restrict__ bl1,
    const int* __restrict__ ids, const float* __restrict__ kg,
    const float* __restrict__ ea, int* __restrict__ relid,
    const float* __restrict__ rel, const float* __restrict__ w2, const float* __restrict__ b2,
    float* __restrict__ W, int* __restrict__ deg, float* __restrict__ S,
    float* __restrict__ x){
  __shared__ float As[8*TOK];                // 24 KB, used by tok section only
  int b = blockIdx.x;
  const int t = threadIdx.x, lane = t&63, wave = t>>6;
  if(b < NB_TOK){
    // x[0:T] = A @ wl1 + bl1 ; 8 rows/block staged in LDS (coalesced), 2 rows/wave
    const int rbase = b*8;
    #pragma unroll
    for(int i=0;i<6;i++){
      int f = t + 256*i;                     // 1536 float4s = 8 rows x 192
      int row = f/192, c4 = (f - row*192)*4;
      *(float4*)&As[row*TOK + c4] = *(const float4*)&A[(size_t)(rbase+row)*TOK + c4];
    }
    __syncthreads();
    const int r0 = wave*2, r1 = r0+1;
    float a0=bl1[lane], a1=a0, c0=0.f, c1=0.f;
    for(int k=0;k<TOK;k+=2){
      float w0 = wl1[(size_t)k*Dd + lane];
      float w1 = wl1[(size_t)(k+1)*Dd + lane];
      a0 += As[r0*TOK+k]*w0;  c0 += As[r0*TOK+k+1]*w1;
      a1 += As[r1*TOK+k]*w0;  c1 += As[r1*TOK+k+1]*w1;
    }
    x[(size_t)(rbase+r0)*Dd + lane] = a0+c0;
    x[(size_t)(rbase+r1)*Dd + lane] = a1+c1;
  } else if(b < NB_TOK+NB_NODES){
    int tt = (b-NB_TOK)*256 + t;             // Nn*16 threads, float4 gather
    int i = tt>>4, c = tt&15;
    ((float4*)x)[(size_t)(Tt+i)*16 + c] = ((const float4*)kg)[(size_t)ids[i]*16 + c];
  } else if(b < NB_TOK+NB_NODES+NB_RELID){
    int tt = (b-NB_TOK-NB_NODES)*256 + t;
    size_t g4 = (size_t)tt*4;
    if(g4 < (size_t)Ee*Rr){
      float4 v = *(const float4*)&ea[g4];
      #pragma unroll
      for(int j=0;j<4;j++){
        if(((const float*)&v)[j] > 0.5f){
          unsigned g = (unsigned)(g4 + j);
          unsigned e = g / 50u;
          relid[e] = (int)(g - e*50u);
        }
      }
    }
  } else if(b < NB_TOK+NB_NODES+NB_RELID+NB_W){
    int tt = (b-NB_TOK-NB_NODES-NB_RELID)*256 + t;   // R*4096
    int r = tt>>12, j = tt&4095;
    float acc = b2[j];
    const float* rp = rel + r*Dd;
    #pragma unroll 8
    for(int d=0;d<Dd;d++) acc += rp[d] * w2[(size_t)d*4096 + j];
    W[tt] = acc > 0.f ? acc : 0.f;
  } else {
    int tt = (b-NB_TOK-NB_NODES-NB_RELID-NB_W)*256 + t;
    if(tt < Mm) deg[tt] = 0;
    else if(tt < Mm+4) S[tt-Mm] = 0.f;
  }
}

// ---------------- K2: fused hist | U | p1 ----------------
__global__ __launch_bounds__(256) void k_mid(const int* __restrict__ ei,
    int* __restrict__ deg, const float* __restrict__ W,
    const float* __restrict__ a1w, const float* __restrict__ a2w,
    float* __restrict__ U1, float* __restrict__ U2,
    const float* __restrict__ x, float* __restrict__ p){
  int b = blockIdx.x;
  const int t = threadIdx.x, lane = t&63, wave = t>>6;
  if(b < NBM_HIST){
    int e = b*256 + t;
    if(e < Ee) atomicAdd(&deg[ei[Ee+e]], 1);
  } else if(b < NBM_HIST+NBM_U){
    int tt = (b-NBM_HIST)*256 + t;           // R*64 = 3200
    if(tt < Rr*Dd){
      const float* wp = W + (size_t)(tt>>6)*4096 + (size_t)(tt&63)*Dd;
      float s1 = 0.f, s2 = 0.f;
      #pragma unroll 8
      for(int o=0;o<Dd;o++){ float w = wp[o]; s1 += w*a1w[Dd+o]; s2 += w*a2w[Dd+o]; }
      U1[tt] = s1; U2[tt] = s2;
    }
  } else {
    int i = (b-NBM_HIST-NBM_U)*4 + wave;     // one row per wave, layer-1 p (no relu)
    float pv = waveRed(x[(size_t)i*Dd + lane] * a1w[lane]);
    if(lane==0) p[i] = pv;
  }
}

// ---------------- CSR scan ----------------
__global__ __launch_bounds__(1024) void k_scan(const int* __restrict__ deg,
    int* __restrict__ rowptr, int* __restrict__ cursor){
  __shared__ int ts[1024];
  int t = threadIdx.x;
  int base = t*24;
  int loc[24];
  int s = 0;
  #pragma unroll
  for(int j=0;j<24;j++){
    int idx = base+j;
    int d = (idx < Mm) ? deg[idx] : 0;
    loc[j] = s; s += d;
  }
  ts[t] = s;
  __syncthreads();
  for(int off=1; off<1024; off<<=1){
    int add = (t>=off) ? ts[t-off] : 0;
    __syncthreads();
    ts[t] += add;
    __syncthreads();
  }
  int excl = ts[t] - s;
  #pragma unroll
  for(int j=0;j<24;j++){
    int idx = base+j;
    if(idx < Mm){ int v = excl + loc[j]; rowptr[idx] = v; cursor[idx] = v; }
  }
  if(t==1023) rowptr[Mm] = ts[1023];
}

// ---------------- fused fill? | attention ----------------
// fill: eidx bucket-fill via cursor atomics (layer 1 only)
// att:  expa[e] = exp(relu?(x[src]).u_r + p[dst] + ab); S += sum
__global__ __launch_bounds__(256) void k_attf(const float* __restrict__ x,
    const int* __restrict__ ei, const int* __restrict__ relid,
    const float* __restrict__ U, const float* __restrict__ p,
    const float* __restrict__ ab, float* __restrict__ expa, float* __restrict__ S,
    int* __restrict__ cursor, int* __restrict__ eidx,
    int dorelu, int dofill){
  __shared__ float sw[4];
  int b = blockIdx.x;
  if(dofill){
    if(b < NBA_FILL){
      int e = b*256 + threadIdx.x;
      if(e < Ee){
        int d = ei[Ee+e];
        int pos = atomicAdd(&cursor[d], 1);
        eidx[pos] = e;
      }
      return;
    }
    b -= NBA_FILL;
  }
  int lane = threadIdx.x&63, wid = threadIdx.x>>6;
  int gw = b*4 + wid;                     // 8192 waves, grid-stride
  float ab0 = ab[0];
  float acc = 0.f;
  for(int e = gw; e < Ee; e += 4*NBA_ATT){
    int src = ei[e], dst = ei[Ee+e], r = relid[e];
    float xv = x[(size_t)src*Dd + lane];
    if(dorelu) xv = fmaxf(xv, 0.f);
    float v = waveRed(xv * U[r*Dd + lane]);
    float ex = expf(v + p[dst] + ab0);    // lane-uniform
    if(lane==0) expa[e] = ex;
    acc += ex;
  }
  if(lane==0) sw[wid] = acc;
  __syncthreads();
  if(threadIdx.x==0) atomicAdd(S, sw[0]+sw[1]+sw[2]+sw[3]);
}

// ---------------- aggregate + fused root matmul (+ next-layer p) ----------------
__global__ __launch_bounds__(256) void k_aggr(const float* __restrict__ x,
    const int* __restrict__ ei, const int* __restrict__ rowptr,
    const int* __restrict__ eidx, const float* __restrict__ expa,
    const float* __restrict__ S, const float* __restrict__ root,
    const float* __restrict__ bias, const float* __restrict__ awn,
    float* __restrict__ y, float* __restrict__ pnext, int dorelu){
  int lane = threadIdx.x&63, wid = threadIdx.x>>6;
  int dst = blockIdx.x*4 + wid;           // grid covers exactly Mm
  float invS = 1.f / S[0];
  int j0 = rowptr[dst], j1 = rowptr[dst+1];
  float acc = 0.f;
  for(int j=j0; j<j1; j++){
    int e = eidx[j];
    float a = expa[e];
    int src = ei[e];
    float xv = x[(size_t)src*Dd + lane];
    if(dorelu) xv = fmaxf(xv, 0.f);
    acc += a*xv;
  }
  acc *= invS;
  float xd = x[(size_t)dst*Dd + lane];
  if(dorelu) xd = fmaxf(xd, 0.f);
  float rsum = bias[lane];
  #pragma unroll 16
  for(int k=0;k<Dd;k++){
    float xk = __shfl(xd, k, 64);
    rsum += xk * root[k*Dd + lane];
  }
  float o = acc + rsum;
  y[(size_t)dst*Dd + lane] = o;
  if(pnext){
    float orl = fmaxf(o, 0.f);            // next layer reads relu(h)
    float pv = waveRed(orl * awn[lane]);
    if(lane==0) pnext[dst] = pv;
  }
}

// ---------------- losses: atomic accumulate into S[2] (kge), S[3] (nt) ----------------
__global__ void k_loss(const float* __restrict__ fx, const int* __restrict__ ei,
    const int* __restrict__ relid, const float* __restrict__ rel,
    const int* __restrict__ lab, const float* __restrict__ wnt,
    const float* __restrict__ bnt, float* __restrict__ S){
  __shared__ float sr[4];
  if(blockIdx.x < 512){
    int wid = threadIdx.x>>6, lane = threadIdx.x&63;
    int gw = blockIdx.x*4 + wid;
    float acc = 0.f;
    for(int e=gw; e<Ee; e+=2048){
      int r = relid[e];
      if(r < 47){
        int src = ei[e], dst = ei[Ee+e];
        float d = fx[(size_t)src*Dd + lane] + rel[r*Dd + lane] - fx[(size_t)dst*Dd + lane];
        acc += d*d;
      }
    }
    acc = waveRed(acc);
    if(lane==0) sr[wid] = acc;
    __syncthreads();
    if(threadIdx.x==0) atomicAdd(&S[2], sr[0]+sr[1]+sr[2]+sr[3]);
  } else {
    int nb = blockIdx.x - 512;
    int i = nb*256 + threadIdx.x;
    float contrib = 0.f;
    if(i < Mm){
      const float* r = fx + (size_t)i*Dd;
      float l0 = bnt[0], l1 = bnt[1], l2 = bnt[2];
      #pragma unroll 8
      for(int k=0;k<Dd;k++){
        float f = r[k];
        l0 += f*wnt[k*3+0]; l1 += f*wnt[k*3+1]; l2 += f*wnt[k*3+2];
      }
      float mx = fmaxf(l0, fmaxf(l1,l2));
      float lse = logf(expf(l0-mx)+expf(l1-mx)+expf(l2-mx)) + mx;
      int lb = lab[i];
      float lp = (lb==0 ? l0 : (lb==1 ? l1 : l2)) - lse;
      contrib = -lp;
    }
    float s = waveRed(contrib);
    if((threadIdx.x&63)==0) sr[threadIdx.x>>6] = s;
    __syncthreads();
    if(threadIdx.x==0) atomicAdd(&S[3], sr[0]+sr[1]+sr[2]+sr[3]);
  }
}

// ---------------- out = fx @ w_lin2 + b_lin2 (+ scalar outputs; k_loss done) ----------------
__global__ __launch_bounds__(256) void k_out(const float* __restrict__ fx,
    const float* __restrict__ w, const float* __restrict__ b,
    const float* __restrict__ S, float* __restrict__ out){
  if(blockIdx.x==0 && blockIdx.y==0 && threadIdx.x==0){
    size_t base = (size_t)Mm*TOK;
    out[base+0] = S[2] / (float)(Ee*Dd);
    out[base+1] = S[3] / (float)Mm;
  }
  __shared__ float aT[Dd][36];
  __shared__ float ws[Dd][128];
  const int t = threadIdx.x;
  const int r0 = blockIdx.x*32, co = blockIdx.y*128;
  #pragma unroll
  for(int i=0;i<2;i++){
    int f = t + 256*i;
    int r = f>>4, k4 = (f&15)*4;
    float4 v = *(const float4*)&fx[(size_t)(r0+r)*Dd + k4];
    aT[k4+0][r]=v.x; aT[k4+1][r]=v.y; aT[k4+2][r]=v.z; aT[k4+3][r]=v.w;
  }
  #pragma unroll
  for(int i=0;i<8;i++){
    int f = t + 256*i;
    int kk = f>>5, c4 = (f&31)*4;
    *(float4*)&ws[kk][c4] = *(const float4*)&w[(size_t)kk*TOK + co + c4];
  }
  __syncthreads();
  const int tr = t>>5, tc = t&31;
  const int rb = tr*4, cb = tc*4;
  float4 bv = *(const float4*)&b[co+cb];
  float acc[4][4];
  #pragma unroll
  for(int i=0;i<4;i++){ acc[i][0]=bv.x; acc[i][1]=bv.y; acc[i][2]=bv.z; acc[i][3]=bv.w; }
  #pragma unroll 8
  for(int k=0;k<Dd;k++){
    float4 a  = *(const float4*)&aT[k][rb];
    float4 wv = *(const float4*)&ws[k][cb];
    #pragma unroll
    for(int i=0;i<4;i++){
      float av = ((const float*)&a)[i];
      acc[i][0] += av*wv.x; acc[i][1] += av*wv.y;
      acc[i][2] += av*wv.z; acc[i][3] += av*wv.w;
    }
  }
  #pragma unroll
  for(int i=0;i<4;i++){
    float4 o; o.x=acc[i][0]; o.y=acc[i][1]; o.z=acc[i][2]; o.w=acc[i][3];
    *(float4*)&out[(size_t)(r0+rb+i)*TOK + co + cb] = o;
  }
}

extern "C" void kernel_launch(void* const* d_in, const int* in_sizes, int n_in,
                              void* d_out, int out_size, void* d_ws, size_t ws_size,
                              hipStream_t stream) {
  const int*   node_ids = (const int*)d_in[0];
  const int*   ei       = (const int*)d_in[1];
  const float* eattr    = (const float*)d_in[2];
  const float* tokemb   = (const float*)d_in[3];
  const int*   labels   = (const int*)d_in[4];
  const float* kg       = (const float*)d_in[5];
  const float* rel      = (const float*)d_in[6];
  const float* w_e2     = (const float*)d_in[7];
  const float* b_e2     = (const float*)d_in[8];
  const float* a1w      = (const float*)d_in[9];
  const float* a1b      = (const float*)d_in[10];
  const float* root1    = (const float*)d_in[11];
  const float* bias1    = (const float*)d_in[12];
  const float* a2w      = (const float*)d_in[13];
  const float* a2b      = (const float*)d_in[14];
  const float* root2    = (const float*)d_in[15];
  const float* bias2    = (const float*)d_in[16];
  const float* wlin1    = (const float*)d_in[17];
  const float* blin1    = (const float*)d_in[18];
  const float* wlin2    = (const float*)d_in[19];
  const float* blin2    = (const float*)d_in[20];
  const float* wnt      = (const float*)d_in[21];
  const float* bnt      = (const float*)d_in[22];

  float* wsb = (float*)d_ws;
  float* x    = wsb;                      // M*64
  float* h    = x  + (size_t)Mm*Dd;
  float* fx   = h  + (size_t)Mm*Dd;
  float* W    = fx + (size_t)Mm*Dd;       // 50*4096
  float* U1   = W  + Rr*4096;             // 3200
  float* U2   = U1 + Rr*Dd;
  float* expa = U2 + Rr*Dd;               // E
  float* p    = expa + Ee;                // M
  float* S    = p + Mm;                   // 4: den1, den2, kge, nt
  int* relid  = (int*)(S + 4);            // E
  int* deg    = relid + Ee;               // M
  int* rowptr = deg + Mm;                 // M+1
  int* cursor = rowptr + Mm + 1;          // M
  int* eidx   = cursor + Mm;              // E
  float* out  = (float*)d_out;

  // ---- prep + CSR ----
  k_prep<<<NB_TOK+NB_NODES+NB_RELID+NB_W+NB_ZERO, 256, 0, stream>>>(
      tokemb, wlin1, blin1, node_ids, kg, eattr, relid, rel, w_e2, b_e2, W, deg, S, x);
  k_mid <<<NBM_HIST+NBM_U+NBM_P, 256, 0, stream>>>(ei, deg, W, a1w, a2w, U1, U2, x, p);
  k_scan<<<1, 1024, 0, stream>>>(deg, rowptr, cursor);

  // ---- layer 1: x -> h (attf also bucket-fills eidx; aggr writes p2 into p) ----
  k_attf<<<NBA_FILL+NBA_ATT, 256, 0, stream>>>(x, ei, relid, U1, p, a1b, expa, S,
                                               cursor, eidx, 0, 1);
  k_aggr<<<Mm/4, 256, 0, stream>>>(x, ei, rowptr, eidx, expa, S, root1, bias1, a2w, h, p, 0);

  // ---- layer 2: relu(h) -> fx ----
  k_attf<<<NBA_ATT, 256, 0, stream>>>(h, ei, relid, U2, p, a2b, expa, S+1,
                                      (int*)0, (int*)0, 1, 0);
  k_aggr<<<Mm/4, 256, 0, stream>>>(h, ei, rowptr, eidx, expa, S+1, root2, bias2,
                                   (const float*)0, fx, (float*)0, 1);

  // ---- losses then output GEMM (+ scalars) ----
  k_loss<<<607, 256, 0, stream>>>(fx, ei, relid, rel, labels, wnt, bnt, S);
  dim3 og(Mm/32, TOK/128);
  k_out <<<og, 256, 0, stream>>>(fx, wlin2, blin2, S, out);
}